// Round 1
// baseline (33.008 us; speedup 1.0000x reference)
//
#include <hip/hip_runtime.h>
#include <hip/hip_bf16.h>

#define L_ 30
#define NB 2
#define NN 64
#define NM 64
#define MCH 16
#define CHUNKS 4

// workspace float offsets
#define O_WOP  0        // 128x128
#define O_BOP  16384    // 128
#define O_WEWK 16512    // 4x128
#define O_WEWV 17024    // 4x128
#define O_CK   17536    // 30x128
#define O_CV   21376    // 30x128
#define O_AE   25216    // 128x128
#define O_QS   41600    // 128x128 (q * 1/sqrt(dh))
#define O_D    57984    // 30*4*128  [(l*4+h)*128+e]
#define O_P    73344    // 16*128    [(h*4+j)*128+e]
#define K1_JOBS 41600
#define K2_JOBS 33792

__device__ __forceinline__ unsigned short f2b(float v) {
    union { float f; unsigned int u; } x; x.f = v;
    unsigned int u = x.u + 0x7FFFu + ((x.u >> 16) & 1u);   // round-to-nearest-even
    return (unsigned short)(u >> 16);
}
__device__ __forceinline__ float b2f(unsigned short s) {
    union { unsigned int u; float f; } x; x.u = ((unsigned int)s) << 16; return x.f;
}
__device__ __forceinline__ float b2f_lo(unsigned int p) {
    union { unsigned int u; float f; } x; x.u = p << 16; return x.f;
}
__device__ __forceinline__ float b2f_hi(unsigned int p) {
    union { unsigned int u; float f; } x; x.u = p & 0xFFFF0000u; return x.f;
}

__global__ __launch_bounds__(256)
void k_pre1(const float* __restrict__ agent,
            const float* __restrict__ We,  const float* __restrict__ be,
            const float* __restrict__ Wa,  const float* __restrict__ ba,
            const float* __restrict__ pe,
            const float* __restrict__ Wk,  const float* __restrict__ bk,
            const float* __restrict__ Wv,  const float* __restrict__ bv,
            const float* __restrict__ Wo,  const float* __restrict__ bo,
            const float* __restrict__ Wp,  const float* __restrict__ bp,
            float* __restrict__ ws) {
    int t = blockIdx.x * 256 + threadIdx.x;
    if (t >= K1_JOBS) return;
    if (t < 16384) {                              // Wop[d][e] = sum_x Wo[d][x] Wp[x][e]
        int d = t >> 7, e = t & 127;
        float a = 0.f;
        for (int x = 0; x < 128; ++x) a += Wo[d*128+x] * Wp[x*128+e];
        ws[O_WOP + t] = a;
    } else if (t < 16512) {                       // bop[e] = bo@Wp + bp
        int e = t - 16384;
        float a = bp[e];
        for (int x = 0; x < 128; ++x) a += bo[x] * Wp[x*128+e];
        ws[O_BOP + e] = a;
    } else if (t < 17024) {                       // WeWk[j][e]
        int i = t - 16512; int j = i >> 7, e = i & 127;
        float a = 0.f;
        for (int d = 0; d < 128; ++d) a += We[j*128+d] * Wk[d*128+e];
        ws[O_WEWK + i] = a;
    } else if (t < 17536) {                       // WeWv[j][e]
        int i = t - 17024; int j = i >> 7, e = i & 127;
        float a = 0.f;
        for (int d = 0; d < 128; ++d) a += We[j*128+d] * Wv[d*128+e];
        ws[O_WEWV + i] = a;
    } else if (t < 21376) {                       // Ck[l][e] = (be+pe[l])@Wk + bk
        int i = t - 17536; int l = i >> 7, e = i & 127;
        float a = bk[e];
        for (int d = 0; d < 128; ++d) a += (be[d] + pe[l*128+d]) * Wk[d*128+e];
        ws[O_CK + i] = a;
    } else if (t < 25216) {                       // Cv[l][e]
        int i = t - 21376; int l = i >> 7, e = i & 127;
        float a = bv[e];
        for (int d = 0; d < 128; ++d) a += (be[d] + pe[l*128+d]) * Wv[d*128+e];
        ws[O_CV + i] = a;
    } else {                                      // ae[r][e] = afeat@Wa + ba
        int i = t - 25216; int r = i >> 7, e = i & 127;
        float a = ba[e];
        const float* ag = agent + r*16;
        a += ag[2] * Wa[0*128+e];
        for (int f = 1; f < 12; ++f) a += ag[4+f] * Wa[f*128+e];
        ws[O_AE + i] = a;
    }
}

__global__ __launch_bounds__(256)
void k_pre2(const float* __restrict__ Wq, const float* __restrict__ bq,
            float* __restrict__ ws) {
    int t = blockIdx.x*256 + threadIdx.x;
    if (t >= K2_JOBS) return;
    if (t < 16384) {                              // qs[r][e] = (ae@Wq + bq)/sqrt(32)
        int r = t >> 7, e = t & 127;
        float a = bq[e];
        const float* ae = ws + O_AE + r*128;
        for (int d = 0; d < 128; ++d) a += ae[d] * Wq[d*128+e];
        ws[O_QS + t] = a * 0.17677669529663687f;
    } else if (t < 31744) {                       // D[(l*4+h)][e] = Cv_h @ Wop_h
        int i = t - 16384; int row = i >> 7, e = i & 127;
        int l = row >> 2, h = row & 3;
        float a = 0.f;
        const float* cv  = ws + O_CV + l*128 + h*32;
        const float* wop = ws + O_WOP + (h*32)*128 + e;
        for (int d = 0; d < 32; ++d) a += cv[d] * wop[d*128];
        ws[O_D + i] = a;
    } else {                                      // P[(h*4+j)][e] = WeWv_h @ Wop_h
        int i = t - 31744; int row = i >> 7, e = i & 127;
        int h = row >> 2, j = row & 3;
        float a = 0.f;
        const float* wv  = ws + O_WEWV + j*128 + h*32;
        const float* wop = ws + O_WOP + (h*32)*128 + e;
        for (int d = 0; d < 32; ++d) a += wv[d] * wop[d*128];
        ws[O_P + i] = a;
    }
}

__global__ __launch_bounds__(256)
void k_main(const float* __restrict__ agent, const float* __restrict__ lane,
            const float* __restrict__ ws, float* __restrict__ out) {

    __shared__ float u_s[16];
    __shared__ float c_s[120];
    __shared__ __align__(16) unsigned short G_s[136][128];   // bf16 [P;D]
    __shared__ __align__(16) unsigned short edge_s[MCH][30][4];
    __shared__ __align__(16) float Wc_s[MCH][140];           // [0..16)=we4, [16..136)=w

    const int t = threadIdx.x;
    const int bid = blockIdx.x;
    const int bn = bid >> 2;            // b*64+n
    const int chunk = bid & 3;
    const int b = bn >> 6;
    const int m0 = chunk * MCH;

    const float* P = ws + O_P;
    const float* D = ws + O_D;

    // stage G = [P(16 rows); D(120 rows, index 16+h*30+l -> D[l][h])] as bf16
    for (int idx = t; idx < 136*128; idx += 256) {
        int i = idx >> 7, e = idx & 127;
        float v;
        if (i < 16) v = P[i*128 + e];
        else { int r = i - 16; int h = r / 30, l = r - h*30; v = D[(l*4 + h)*128 + e]; }
        G_s[i][e] = f2b(v);
    }
    // per-agent u (4x4) and c (4x30)
    if (t < 136) {
        const float* q = ws + O_QS + bn*128;
        if (t < 16) {
            int h = t >> 2, j = t & 3;
            const float* wk = ws + O_WEWK + j*128 + h*32;
            const float* qh = q + h*32;
            float a = 0.f;
            for (int d = 0; d < 32; ++d) a += wk[d] * qh[d];
            u_s[t] = a;
        } else {
            int r = t - 16; int h = r / 30, l = r - h*30;
            const float* ck = ws + O_CK + l*128 + h*32;
            const float* qh = q + h*32;
            float a = 0.f;
            for (int d = 0; d < 32; ++d) a += ck[d] * qh[d];
            c_s[r] = a;
        }
    }
    const float ax  = agent[bn*16+0], ay = agent[bn*16+1];
    const float as_ = agent[bn*16+3], ac = agent[bn*16+4];
    const float f1 = (ax==0.f && ay==0.f && as_==0.f && ac==0.f) ? 0.f : 1.f;
    __syncthreads();

    // B1: edges (bf16 to LDS) + raw scores into Wc_s[m][16+h*30+l]
    for (int job = t; job < MCH*30; job += 256) {
        int m = job / 30, l = job - m*30;
        const float* lp = lane + (size_t)((b*NM + m0 + m)*L_ + l)*4;
        float4 lv = *(const float4*)lp;
        float f2 = (lv.x==0.f && lv.y==0.f && lv.z==0.f && lv.w==0.f) ? 0.f : 1.f;
        float f = f1 * f2;
        float dx = lv.x - ax, dy = lv.y - ay;
        float rx = (ac*dx + as_*dy) * 0.1f * f;
        float ry = (ac*dy - as_*dx) * 0.1f * f;
        float rs = (lv.z*ac - lv.w*as_) * f;
        float rc = (lv.w*ac + lv.z*as_) * f;
        unsigned int p0 = (unsigned int)f2b(rx) | ((unsigned int)f2b(ry) << 16);
        unsigned int p1 = (unsigned int)f2b(rs) | ((unsigned int)f2b(rc) << 16);
        *(uint2*)&edge_s[m][l][0] = make_uint2(p0, p1);
        #pragma unroll
        for (int h = 0; h < 4; ++h) {
            float s = rx*u_s[h*4+0] + ry*u_s[h*4+1] + rs*u_s[h*4+2] + rc*u_s[h*4+3]
                    + c_s[h*30+l];
            Wc_s[m][16 + h*30 + l] = s;
        }
    }
    __syncthreads();
    // B2: softmax over l per (m,h)
    if (t < MCH*4) {
        int m = t >> 2, h = t & 3;
        float* s = &Wc_s[m][16 + h*30];
        float mx = s[0];
        for (int l = 1; l < 30; ++l) mx = fmaxf(mx, s[l]);
        float sum = 0.f;
        for (int l = 0; l < 30; ++l) { float e = __expf(s[l]-mx); s[l] = e; sum += e; }
        float inv = 1.f / sum;
        for (int l = 0; l < 30; ++l) s[l] *= inv;
    }
    __syncthreads();
    // B3: we4[m][h*4+j] = sum_l w * edge_j   (256 jobs exactly)
    {
        int m = t >> 4, i = t & 15;
        int h = i >> 2, j = i & 3;
        float a = 0.f;
        for (int l = 0; l < 30; ++l)
            a += Wc_s[m][16 + h*30 + l] * b2f(edge_s[m][l][j]);
        Wc_s[m][i] = a;
    }
    __syncthreads();
    // C: OUT[16m x 128e] = Wc[16x136] @ G[136x128] + bop ; tile 2m x 4e per thread
    {
        const int em = t & 31, r = t >> 5;
        const int e0 = em * 4;
        const int mA = r, mB = r + 8;
        float4 bb = *(const float4*)(ws + O_BOP + e0);
        float aA0=bb.x,aA1=bb.y,aA2=bb.z,aA3=bb.w;
        float aB0=bb.x,aB1=bb.y,aB2=bb.z,aB3=bb.w;
        for (int i = 0; i < 136; i += 4) {
            float4 wa = *(const float4*)&Wc_s[mA][i];
            float4 wb = *(const float4*)&Wc_s[mB][i];
            float wav[4] = {wa.x, wa.y, wa.z, wa.w};
            float wbv[4] = {wb.x, wb.y, wb.z, wb.w};
            #pragma unroll
            for (int di = 0; di < 4; ++di) {
                uint2 g = *(const uint2*)&G_s[i+di][e0];
                float g0 = b2f_lo(g.x), g1 = b2f_hi(g.x);
                float g2 = b2f_lo(g.y), g3 = b2f_hi(g.y);
                aA0 += wav[di]*g0; aA1 += wav[di]*g1; aA2 += wav[di]*g2; aA3 += wav[di]*g3;
                aB0 += wbv[di]*g0; aB1 += wbv[di]*g1; aB2 += wbv[di]*g2; aB3 += wbv[di]*g3;
            }
        }
        size_t baseA = ((size_t)(bn*NM + m0 + mA))*128 + e0;
        size_t baseB = ((size_t)(bn*NM + m0 + mB))*128 + e0;
        *(float4*)(out + baseA) = make_float4(aA0,aA1,aA2,aA3);
        *(float4*)(out + baseB) = make_float4(aB0,aB1,aB2,aB3);
    }
}

extern "C" void kernel_launch(void* const* d_in, const int* in_sizes, int n_in,
                              void* d_out, int out_size, void* d_ws, size_t ws_size,
                              hipStream_t stream) {
    const float* agent = (const float*)d_in[0];
    const float* lane  = (const float*)d_in[1];
    const float* We = (const float*)d_in[2];
    const float* be = (const float*)d_in[3];
    const float* Wa = (const float*)d_in[4];
    const float* ba = (const float*)d_in[5];
    const float* pe = (const float*)d_in[6];
    const float* Wq = (const float*)d_in[7];
    const float* bq = (const float*)d_in[8];
    const float* Wk = (const float*)d_in[9];
    const float* bk = (const float*)d_in[10];
    const float* Wv = (const float*)d_in[11];
    const float* bv = (const float*)d_in[12];
    const float* Wo = (const float*)d_in[13];
    const float* bo = (const float*)d_in[14];
    const float* Wp = (const float*)d_in[15];
    const float* bp = (const float*)d_in[16];
    float* ws  = (float*)d_ws;
    float* out = (float*)d_out;

    hipLaunchKernelGGL(k_pre1, dim3((K1_JOBS+255)/256), dim3(256), 0, stream,
                       agent, We, be, Wa, ba, pe, Wk, bk, Wv, bv, Wo, bo, Wp, bp, ws);
    hipLaunchKernelGGL(k_pre2, dim3((K2_JOBS+255)/256), dim3(256), 0, stream, Wq, bq, ws);
    hipLaunchKernelGGL(k_main, dim3(NB*NN*CHUNKS), dim3(256), 0, stream,
                       agent, lane, ws, out);
}